// Round 2
// baseline (113.852 us; speedup 1.0000x reference)
//
#include <hip/hip_runtime.h>
#include <math.h>

// Problem constants (fixed by reference setup_inputs)
#define P_    256           // identities
#define K_    16            // instances per group
#define C_    4096          // feature dim
#define C4_   (C_/4)        // 1024 float4 per row
#define N_    8192          // 2*P*K rows
#define TWOP  512           // groups
#define HALF  4096          // N/2
#define W4    64            // float4 per slice (= 256 floats)
#define NSL   16            // C_/(W4*4) slices
#define NPOSTB 32           // k_post blocks (8192 threads)
#define NSCRB  32           // k_screen blocks
#define MARGIN_F 0.6f
#define EXCAP   4096
#define FLAGCAP 16384

__device__ __forceinline__ void wave_reduce2(float& a, float& b) {
    #pragma unroll
    for (int o = 32; o > 0; o >>= 1) {
        a += __shfl_xor(a, o, 64);
        b += __shfl_xor(b, o, 64);
    }
}
__device__ __forceinline__ float wave_reduce_f(float v) {
    #pragma unroll
    for (int o = 32; o > 0; o >>= 1) v += __shfl_xor(v, o, 64);
    return v;
}
__device__ __forceinline__ unsigned wave_reduce_u(unsigned v) {
    #pragma unroll
    for (int o = 32; o > 0; o >>= 1) v += __shfl_xor(v, o, 64);
    return v;
}

// ---------------------------------------------------------------------------
// k_fused: one block per (pair p, column slice s). Stages the 32 rows of the
// group pair's slice in LDS; computes both center slices, writes hcen slice,
// and per-slice partials: dot(x_i, h_partner), |x_i|^2, |h|^2.
// x is read exactly once across the whole grid.
__global__ __launch_bounds__(256) void k_fused(const float* __restrict__ x,
                                               float* __restrict__ hcen,
                                               float* __restrict__ dot_part,
                                               float* __restrict__ sq_part,
                                               float* __restrict__ hn2_part) {
    const int blk = blockIdx.x;
    const int p = blk >> 4;          // pair id 0..255
    const int s = blk & (NSL - 1);   // slice 0..15
    const int t = threadIdx.x;
    const int lane = t & 63;
    const int wv = t >> 6;           // wave 0..3

    __shared__ float4 xs[32][W4];    // 32 KB
    __shared__ float4 hA[W4], hB[W4];

    const float4* x4 = (const float4*)x;
    const int colbase = s * W4 + lane;

    // ---- load: rows r = q*4 + wv, lanes cover the 64 float4 of the slice
    float4 v[8];
    #pragma unroll
    for (int q = 0; q < 8; ++q) {
        const int r = q * 4 + wv;
        const int grp = (r < 16) ? p : (P_ + p);
        const size_t gr = (size_t)grp * K_ + (r & 15);
        v[q] = x4[gr * C4_ + colbase];
    }
    #pragma unroll
    for (int q = 0; q < 8; ++q) {
        const int r = q * 4 + wv;
        xs[r][lane] = v[q];
    }
    __syncthreads();

    // ---- centers: wave0 -> hA (rows 0..15), wave1 -> hB (rows 16..31)
    if (wv < 2) {
        const int rbase = wv * 16;
        float4 a = {0.f, 0.f, 0.f, 0.f};
        #pragma unroll
        for (int r = 0; r < 16; ++r) {
            float4 u = xs[rbase + r][lane];
            a.x += u.x; a.y += u.y; a.z += u.z; a.w += u.w;
        }
        const float sc = 1.0f / (float)K_;
        a.x *= sc; a.y *= sc; a.z *= sc; a.w *= sc;
        if (wv == 0) hA[lane] = a; else hB[lane] = a;
        // global hcen slice write (coalesced 1 KB)
        const int grp = (wv == 0) ? p : (P_ + p);
        ((float4*)hcen)[(size_t)grp * C4_ + s * W4 + lane] = a;
        // center sq-norm partial
        float hn = a.x*a.x + a.y*a.y + a.z*a.z + a.w*a.w;
        hn = wave_reduce_f(hn);
        if (lane == 0) hn2_part[(p * NSL + s) * 2 + wv] = hn;
    }
    __syncthreads();

    // ---- dots: wave wv owns rows wv*8 .. wv*8+7; rows<16 pair with hB, else hA
    const float4 h = (wv < 2) ? hB[lane] : hA[lane];
    const int outbase = (p * NSL + s) * 32;
    #pragma unroll
    for (int rr = 0; rr < 8; ++rr) {
        const int r = wv * 8 + rr;
        const float4 a = xs[r][lane];
        float dp = a.x*h.x + a.y*h.y + a.z*h.z + a.w*h.w;
        float sq = a.x*a.x + a.y*a.y + a.z*a.z + a.w*a.w;
        wave_reduce2(dp, sq);
        if (lane == 0) {
            dot_part[outbase + r] = dp;
            sq_part[outbase + r]  = sq;
        }
    }
}

// ---------------------------------------------------------------------------
// k_post: one thread per (pair, row). Combines slice partials -> dist to the
// partner center; pid matchscan (general-pids correctness): counts matches,
// flags non-partner matches for exact correction. Emits xn (=|x_i|), hn
// (=|h_g|), per-block loss1 partial sums and match counts.
__global__ __launch_bounds__(256) void k_post(const float* __restrict__ dot_part,
                                              const float* __restrict__ sq_part,
                                              const float* __restrict__ hn2_part,
                                              const int* __restrict__ pids,
                                              float* __restrict__ xn,
                                              float* __restrict__ hn,
                                              float* __restrict__ s1part,
                                              unsigned* __restrict__ cnt1part,
                                              unsigned* __restrict__ extracnt,
                                              int* __restrict__ extralist,
                                              unsigned* __restrict__ ovf) {
    __shared__ int gp[TWOP];
    __shared__ float rf[4];
    __shared__ unsigned ru[4];
    const int t = threadIdx.x;
    for (int j = t; j < TWOP; j += 256) gp[j] = pids[j * K_];
    __syncthreads();

    const int idx = blockIdx.x * 256 + t;   // 0..8191
    const int p = idx >> 5, r = idx & 31;
    const int hsel = (r < 16) ? 1 : 0;      // partner center: A-rows -> B(=1), B-rows -> A(=0)

    float dot = 0.f, sq = 0.f, hn2 = 0.f;
    #pragma unroll 4
    for (int s = 0; s < NSL; ++s) {
        dot += dot_part[(p * NSL + s) * 32 + r];
        sq  += sq_part [(p * NSL + s) * 32 + r];
        hn2 += hn2_part[(p * NSL + s) * 2 + hsel];
    }
    const int gr = (r < 16) ? p * K_ + r : (P_ + p) * K_ + (r - 16);
    const float dist = sqrtf(fmaxf(sq + hn2 - 2.0f * dot, 1e-12f));
    xn[gr] = sqrtf(sq);
    if (r == 16) hn[p]      = sqrtf(hn2);   // this thread summed A-center norm
    if (r == 0)  hn[P_ + p] = sqrtf(hn2);   // this thread summed B-center norm

    // matchscan over the opposite-modality centers (general pids)
    const int mypid = pids[gr];
    const int jbase = (gr < HALF) ? P_ : 0;
    const int pg    = (gr < HALF) ? P_ + p : p;   // structural partner group
    unsigned m = 0;
    for (int j = 0; j < P_; ++j) {
        const int jj = jbase + j;
        if (gp[jj] == mypid) {
            ++m;
            if (jj != pg) {
                unsigned s0 = atomicAdd(extracnt, 1u);
                if (s0 < EXCAP) extralist[s0] = gr * TWOP + jj;
                else atomicExch(ovf, 1u);
            }
        }
    }
    float c1 = (gp[pg] == mypid) ? dist : 0.f;

    // block reduce: loss1 partial + match count
    unsigned mv = m;
    #pragma unroll
    for (int o = 32; o > 0; o >>= 1) {
        c1 += __shfl_xor(c1, o, 64);
        mv += __shfl_xor(mv, o, 64);
    }
    if ((t & 63) == 0) { rf[t >> 6] = c1; ru[t >> 6] = mv; }
    __syncthreads();
    if (t == 0) {
        s1part[blockIdx.x]   = rf[0] + rf[1] + rf[2] + rf[3];
        cnt1part[blockIdx.x] = ru[0] + ru[1] + ru[2] + ru[3];
    }
}

// ---------------------------------------------------------------------------
// k_screen: all (row, center) pairs. Counts negatives; reverse-triangle bound
// dist >= |xn - hn| proves hinge==0 unless bound < margin (then flag exact).
__global__ __launch_bounds__(256) void k_screen(const int* __restrict__ pids,
                                                const float* __restrict__ xn,
                                                const float* __restrict__ hn,
                                                unsigned* __restrict__ negpart,
                                                unsigned* __restrict__ flagcnt,
                                                int* __restrict__ flaglist,
                                                unsigned* __restrict__ ovf) {
    __shared__ float shn[TWOP];
    __shared__ int   sgp[TWOP];
    __shared__ unsigned ru[4];
    const int t = threadIdx.x;
    for (int j = t; j < TWOP; j += 256) { shn[j] = hn[j]; sgp[j] = pids[j * K_]; }
    __syncthreads();

    const int i = blockIdx.x * 256 + t;   // row
    const float myxn = xn[i];
    const int mypid = pids[i];
    unsigned neg = 0;
    for (int j = 0; j < TWOP; ++j) {
        if (sgp[j] != mypid) {
            ++neg;
            if (fabsf(myxn - shn[j]) < MARGIN_F) {
                unsigned s0 = atomicAdd(flagcnt, 1u);
                if (s0 < FLAGCAP) flaglist[s0] = i * TWOP + j;
                else atomicExch(ovf, 1u);
            }
        }
    }
    neg = wave_reduce_u(neg);
    if ((t & 63) == 0) ru[t >> 6] = neg;
    __syncthreads();
    if (t == 0) negpart[blockIdx.x] = ru[0] + ru[1] + ru[2] + ru[3];
}

// ---------------------------------------------------------------------------
// k_exact: exact distances for flagged pairs (extras -> loss1 add; screen
// flags -> hinge add). Expected empty for this data; kept for faithfulness.
__global__ __launch_bounds__(256) void k_exact(const float* __restrict__ x,
                                               const float* __restrict__ hcen,
                                               const float* __restrict__ xn,
                                               const float* __restrict__ hn,
                                               const unsigned* __restrict__ extracnt,
                                               const int* __restrict__ extralist,
                                               const unsigned* __restrict__ flagcnt,
                                               const int* __restrict__ flaglist,
                                               float* __restrict__ s1x,
                                               float* __restrict__ l2sum) {
    unsigned ne = *extracnt; if (ne > EXCAP)   ne = EXCAP;
    unsigned nf = *flagcnt;  if (nf > FLAGCAP) nf = FLAGCAP;
    const unsigned tot = ne + nf;
    const int t = threadIdx.x;
    __shared__ float red[4];
    for (unsigned u = blockIdx.x; u < tot; u += gridDim.x) {
        const bool isex = (u < ne);
        const int code = isex ? extralist[u] : flaglist[u - ne];
        const int i = code >> 9, jj = code & (TWOP - 1);
        const float4* xr = (const float4*)(x + (size_t)i * C_);
        const float4* hr = (const float4*)(hcen + (size_t)jj * C_);
        float d = 0.f;
        for (int c = t; c < C4_; c += 256) {
            float4 a = xr[c], b = hr[c];
            d += a.x*b.x + a.y*b.y + a.z*b.z + a.w*b.w;
        }
        d = wave_reduce_f(d);
        if ((t & 63) == 0) red[t >> 6] = d;
        __syncthreads();
        if (t == 0) {
            const float dt = red[0] + red[1] + red[2] + red[3];
            const float d2 = xn[i]*xn[i] + hn[jj]*hn[jj] - 2.0f * dt;
            const float dist = sqrtf(fmaxf(d2, 1e-12f));
            if (isex) atomicAdd(s1x, dist);
            else { float h = MARGIN_F - dist; if (h > 0.f) atomicAdd(l2sum, h); }
        }
        __syncthreads();
    }
}

// ---------------------------------------------------------------------------
// k_final: deterministic scalar assembly.
__global__ __launch_bounds__(64) void k_final(const float* __restrict__ s1part,
                                              const unsigned* __restrict__ cnt1part,
                                              const unsigned* __restrict__ negpart,
                                              const float* __restrict__ s1x,
                                              const float* __restrict__ l2sum,
                                              float* __restrict__ out) {
    const int t = threadIdx.x;
    float s1 = (t < NPOSTB) ? s1part[t] : 0.f;
    unsigned c1 = (t < NPOSTB) ? cnt1part[t] : 0u;
    unsigned ng = (t < NSCRB) ? negpart[t] : 0u;
    s1 = wave_reduce_f(s1);
    c1 = wave_reduce_u(c1);
    ng = wave_reduce_u(ng);
    if (t == 0) {
        const float S1 = s1 + *s1x;
        out[0] = S1 / (float)c1 + l2sum[0] / (float)ng;
    }
}

// ---------------------------------------------------------------------------
extern "C" void kernel_launch(void* const* d_in, const int* in_sizes, int n_in,
                              void* d_out, int out_size, void* d_ws, size_t ws_size,
                              hipStream_t stream) {
    const float* x    = (const float*)d_in[0];
    const int*   pids = (const int*)d_in[1];

    float* ws = (float*)d_ws;
    float*    hcen     = ws;                                    // 512*4096 = 2,097,152
    float*    dot_part = hcen + (size_t)TWOP * C_;              // 131072
    float*    sq_part  = dot_part + P_ * NSL * 32;              // 131072
    float*    hn2_part = sq_part + P_ * NSL * 32;               // 8192
    float*    xn       = hn2_part + P_ * NSL * 2;               // 8192
    float*    hn       = xn + N_;                               // 512
    float*    s1part   = hn + TWOP;                             // 32
    unsigned* cnt1part = (unsigned*)(s1part + NPOSTB);          // 32
    unsigned* negpart  = cnt1part + NPOSTB;                     // 32
    float*    counters = (float*)(negpart + NSCRB);             // [l2sum, s1x, extracnt, flagcnt, ovf]
    float*    l2sum    = counters;
    float*    s1x      = counters + 1;
    unsigned* extracnt = (unsigned*)(counters + 2);
    unsigned* flagcnt  = (unsigned*)(counters + 3);
    unsigned* ovf      = (unsigned*)(counters + 4);
    int*      extralist= (int*)(counters + 5);                  // EXCAP
    int*      flaglist = extralist + EXCAP;                     // FLAGCAP

    hipMemsetAsync(counters, 0, 5 * sizeof(float), stream);
    hipLaunchKernelGGL(k_fused,  dim3(P_ * NSL), dim3(256), 0, stream,
                       x, hcen, dot_part, sq_part, hn2_part);
    hipLaunchKernelGGL(k_post,   dim3(NPOSTB),   dim3(256), 0, stream,
                       dot_part, sq_part, hn2_part, pids, xn, hn,
                       s1part, cnt1part, extracnt, extralist, ovf);
    hipLaunchKernelGGL(k_screen, dim3(NSCRB),    dim3(256), 0, stream,
                       pids, xn, hn, negpart, flagcnt, flaglist, ovf);
    hipLaunchKernelGGL(k_exact,  dim3(64),       dim3(256), 0, stream,
                       x, hcen, xn, hn, extracnt, extralist, flagcnt, flaglist,
                       s1x, l2sum);
    hipLaunchKernelGGL(k_final,  dim3(1),        dim3(64),  0, stream,
                       s1part, cnt1part, negpart, s1x, l2sum, (float*)d_out);
}

// Round 3
// 39.928 us; speedup vs baseline: 2.8514x; 2.8514x over previous
//
#include <hip/hip_runtime.h>
#include <math.h>

// Problem constants (fixed by reference setup_inputs)
#define P_    256           // identities
#define K_    16            // instances per group
#define C_    4096          // feature dim
#define C4_   1024          // float4 per row
#define N_    8192          // 2*P*K rows
#define TWOP  512           // groups
#define NSL   16            // column slices
#define W4    64            // float4 per slice (256 floats)
#define NTAILB 32           // k_tail blocks (32*256 = 8192 threads = one per row)
#define MARGIN_F 0.6f
#define EXCAP   8192
#define FLAGCAP 16384

__device__ __forceinline__ float wave_reduce_f(float v) {
    #pragma unroll
    for (int o = 32; o > 0; o >>= 1) v += __shfl_xor(v, o, 64);
    return v;
}

// ---------------------------------------------------------------------------
// k_fused: one block per (pair p, slice s). Register-resident: each wave loads
// 8 row-slices (4 A-rows, 4 B-rows) into v[8]; centers via per-wave partial
// sums combined in LDS (10 KB). Emits per-slice partials for dot(x_i, h_partner),
// |x_i|^2, |h|^2. x read exactly once. Block 0 zeroes the counters.
__global__ __launch_bounds__(256) void k_fused(const float* __restrict__ x,
                                               float* __restrict__ dot_part,
                                               float* __restrict__ sq_part,
                                               float* __restrict__ hn2_part,
                                               unsigned* __restrict__ counters) {
    const int blk = blockIdx.x;
    const int p = blk >> 4;          // pair id 0..255
    const int s = blk & (NSL - 1);   // slice 0..15
    const int t = threadIdx.x;
    const int lane = t & 63;
    const int wv = t >> 6;           // wave 0..3

    if (blk == 0 && t < 3) counters[t] = 0u;   // extracnt, flagcnt, ovf

    __shared__ float4 partA[4][W4];  // 4 KB
    __shared__ float4 partB[4][W4];  // 4 KB
    __shared__ float4 shA[W4];       // 1 KB
    __shared__ float4 shB[W4];       // 1 KB

    const float4* x4 = (const float4*)x;
    const int col = s * W4 + lane;

    // wave wv owns rows r = q*4 + wv: q<4 -> A-rows (grp p), q>=4 -> B-rows (grp P_+p)
    float4 v[8];
    #pragma unroll
    for (int q = 0; q < 8; ++q) {
        const int r = q * 4 + wv;
        const int grp = (r < 16) ? p : (P_ + p);
        v[q] = x4[((size_t)grp * K_ + (r & 15)) * C4_ + col];
    }
    float4 sA = {0.f,0.f,0.f,0.f}, sB = {0.f,0.f,0.f,0.f};
    #pragma unroll
    for (int q = 0; q < 4; ++q) { sA.x += v[q].x; sA.y += v[q].y; sA.z += v[q].z; sA.w += v[q].w; }
    #pragma unroll
    for (int q = 4; q < 8; ++q) { sB.x += v[q].x; sB.y += v[q].y; sB.z += v[q].z; sB.w += v[q].w; }
    partA[wv][lane] = sA;
    partB[wv][lane] = sB;
    __syncthreads();

    if (wv < 2) {
        float4 a;
        if (wv == 0) {
            float4 u0 = partA[0][lane], u1 = partA[1][lane], u2 = partA[2][lane], u3 = partA[3][lane];
            a.x = (u0.x+u1.x+u2.x+u3.x) * 0.0625f;
            a.y = (u0.y+u1.y+u2.y+u3.y) * 0.0625f;
            a.z = (u0.z+u1.z+u2.z+u3.z) * 0.0625f;
            a.w = (u0.w+u1.w+u2.w+u3.w) * 0.0625f;
            shA[lane] = a;
        } else {
            float4 u0 = partB[0][lane], u1 = partB[1][lane], u2 = partB[2][lane], u3 = partB[3][lane];
            a.x = (u0.x+u1.x+u2.x+u3.x) * 0.0625f;
            a.y = (u0.y+u1.y+u2.y+u3.y) * 0.0625f;
            a.z = (u0.z+u1.z+u2.z+u3.z) * 0.0625f;
            a.w = (u0.w+u1.w+u2.w+u3.w) * 0.0625f;
            shB[lane] = a;
        }
        float hn = a.x*a.x + a.y*a.y + a.z*a.z + a.w*a.w;
        hn = wave_reduce_f(hn);
        if (lane == 0) hn2_part[(p * NSL + s) * 2 + wv] = hn;   // side 0 = A(grp p), 1 = B
    }
    __syncthreads();

    const float4 hA = shA[lane];
    const float4 hB = shB[lane];
    const int outbase = (p * NSL + s) * 32;
    #pragma unroll
    for (int q = 0; q < 8; ++q) {
        const float4 a = v[q];
        const float4 h = (q < 4) ? hB : hA;    // A-rows pair with B-center and vice versa
        float dp = a.x*h.x + a.y*h.y + a.z*h.z + a.w*h.w;
        float sq = a.x*a.x + a.y*a.y + a.z*a.z + a.w*a.w;
        #pragma unroll
        for (int o = 32; o > 0; o >>= 1) {
            dp += __shfl_xor(dp, o, 64);
            sq += __shfl_xor(sq, o, 64);
        }
        if (lane == 0) {
            dot_part[outbase + q*4 + wv] = dp;
            sq_part [outbase + q*4 + wv] = sq;
        }
    }
}

// ---------------------------------------------------------------------------
// k_tail: one thread per row. Combines slice partials -> dist/xn; structured
// fast path (no per-row scan) when pids match the canonical layout AND the
// norm-window proves all hinges zero; otherwise exact per-row scan with
// extra/flag push. Emits per-block loss1 partial, match count, neg count.
__global__ __launch_bounds__(256) void k_tail(const float* __restrict__ dot_part,
                                              const float* __restrict__ sq_part,
                                              const float* __restrict__ hn2_part,
                                              const int* __restrict__ pids,
                                              float* __restrict__ xn,
                                              float* __restrict__ hng2,
                                              float* __restrict__ s1part,
                                              unsigned* __restrict__ c1part,
                                              unsigned* __restrict__ negpart,
                                              unsigned* __restrict__ counters,
                                              int* __restrict__ extralist,
                                              int* __restrict__ flaglist) {
    __shared__ int   gp[TWOP];
    __shared__ float shn[TWOP];
    __shared__ float sh2[TWOP];
    __shared__ int   s_ok;
    __shared__ float s_min[4], s_max[4];
    __shared__ float rf[4];
    __shared__ unsigned ru[4], rn[4];
    const int t = threadIdx.x;
    const int lane = t & 63, wv = t >> 6;

    if (t == 0) s_ok = 1;
    __syncthreads();

    float lmin = 3.0e38f, lmax = -3.0e38f;
    for (int j = t; j < TWOP; j += 256) {
        const int g = pids[j * K_];
        gp[j] = g;
        if (g != (j & (P_ - 1))) s_ok = 0;     // structured-layout check (writes 0 only)
        const int side = (j < P_) ? 0 : 1;
        const int pp = j & (P_ - 1);
        float a = 0.f;
        #pragma unroll
        for (int s = 0; s < NSL; ++s) a += hn2_part[(pp * NSL + s) * 2 + side];
        sh2[j] = a;
        const float r = sqrtf(a);
        shn[j] = r;
        lmin = fminf(lmin, r); lmax = fmaxf(lmax, r);
    }
    #pragma unroll
    for (int o = 32; o > 0; o >>= 1) {
        lmin = fminf(lmin, __shfl_xor(lmin, o, 64));
        lmax = fmaxf(lmax, __shfl_xor(lmax, o, 64));
    }
    if (lane == 0) { s_min[wv] = lmin; s_max[wv] = lmax; }
    __syncthreads();
    const float hmin = fminf(fminf(s_min[0], s_min[1]), fminf(s_min[2], s_min[3]));
    const float hmax = fmaxf(fmaxf(s_max[0], s_max[1]), fmaxf(s_max[2], s_max[3]));
    const int structured = s_ok;

    if (blockIdx.x == 0)
        for (int j = t; j < TWOP; j += 256) hng2[j] = sh2[j];

    const int gr  = blockIdx.x * 256 + t;     // row 0..8191
    const int grp = gr >> 4, kk = gr & 15;
    const int p   = grp & (P_ - 1);
    const int r   = (grp < P_) ? kk : 16 + kk;
    const int pg  = (grp < P_) ? (P_ + p) : p;   // structural partner group

    float dot = 0.f, sq = 0.f;
    #pragma unroll
    for (int s = 0; s < NSL; ++s) {
        dot += dot_part[(p * NSL + s) * 32 + r];
        sq  += sq_part [(p * NSL + s) * 32 + r];
    }
    const float dist = sqrtf(fmaxf(sq + sh2[pg] - 2.0f * dot, 1e-12f));
    const float myxn = sqrtf(sq);
    xn[gr] = myxn;

    const int mypid = pids[gr];
    const bool window_clear = (myxn >= hmax + MARGIN_F) || (myxn <= hmin - MARGIN_F);

    unsigned mall, mopp;
    if (structured && mypid == p && window_clear) {
        // canonical layout: exactly 2 matches (groups p and P_+p), 1 cross-modal,
        // no extras; window proves every hinge is zero.
        mall = 2u; mopp = 1u;
    } else {
        const int jb = (gr < N_ / 2) ? P_ : 0;   // opposite-half base
        mall = 0u; mopp = 0u;
        for (int j = 0; j < TWOP; ++j) {
            if (gp[j] == mypid) {
                ++mall;
                if (j >= jb && j < jb + P_) {
                    ++mopp;
                    if (j != pg) {
                        unsigned s0 = atomicAdd(&counters[0], 1u);
                        if (s0 < EXCAP) extralist[s0] = gr * TWOP + j;
                        else atomicExch(&counters[2], 1u);
                    }
                }
            } else {
                if (fabsf(myxn - shn[j]) < MARGIN_F) {
                    unsigned s0 = atomicAdd(&counters[1], 1u);
                    if (s0 < FLAGCAP) flaglist[s0] = gr * TWOP + j;
                    else atomicExch(&counters[2], 1u);
                }
            }
        }
    }

    float s1 = (gp[pg] == mypid) ? dist : 0.f;
    unsigned neg = (unsigned)TWOP - mall;
    unsigned mo = mopp;
    #pragma unroll
    for (int o = 32; o > 0; o >>= 1) {
        s1  += __shfl_xor(s1, o, 64);
        mo  += __shfl_xor(mo, o, 64);
        neg += __shfl_xor(neg, o, 64);
    }
    if (lane == 0) { rf[wv] = s1; ru[wv] = mo; rn[wv] = neg; }
    __syncthreads();
    if (t == 0) {
        s1part[blockIdx.x]  = rf[0] + rf[1] + rf[2] + rf[3];
        c1part[blockIdx.x]  = ru[0] + ru[1] + ru[2] + ru[3];
        negpart[blockIdx.x] = rn[0] + rn[1] + rn[2] + rn[3];
    }
}

// ---------------------------------------------------------------------------
// k_final: reduce partials; exact path for extras (loss1 add) and flagged
// pairs (hinge add) recomputing h from x (expected zero pairs); emit scalar.
__global__ __launch_bounds__(256) void k_final(const float* __restrict__ x,
                                               const float* __restrict__ xn,
                                               const float* __restrict__ hng2,
                                               const float* __restrict__ s1part,
                                               const unsigned* __restrict__ c1part,
                                               const unsigned* __restrict__ negpart,
                                               const unsigned* __restrict__ counters,
                                               const int* __restrict__ extralist,
                                               const int* __restrict__ flaglist,
                                               float* __restrict__ out) {
    const int t = threadIdx.x;
    const int lane = t & 63;
    __shared__ float red[4];
    __shared__ float sS1, sC1, sNG;

    {
        float s1 = 0.f; unsigned c1 = 0u, ng = 0u;
        if (t < NTAILB) { s1 = s1part[t]; c1 = c1part[t]; ng = negpart[t]; }
        if (t < 64) {
            #pragma unroll
            for (int o = 32; o > 0; o >>= 1) {
                s1 += __shfl_xor(s1, o, 64);
                c1 += __shfl_xor(c1, o, 64);
                ng += __shfl_xor(ng, o, 64);
            }
            if (t == 0) { sS1 = s1; sC1 = (float)c1; sNG = (float)ng; }
        }
    }
    __syncthreads();

    unsigned ne = counters[0]; if (ne > EXCAP)   ne = EXCAP;
    unsigned nf = counters[1]; if (nf > FLAGCAP) nf = FLAGCAP;
    float s1x = 0.f, l2 = 0.f;
    const float4* x4 = (const float4*)x;
    for (unsigned u = 0; u < ne + nf; ++u) {
        const bool isex = (u < ne);
        const int code = isex ? extralist[u] : flaglist[u - ne];
        const int i = code >> 9, jj = code & (TWOP - 1);
        const float4* xr = x4 + (size_t)i * C4_;
        const float4* gb = x4 + (size_t)jj * K_ * C4_;
        float dp = 0.f;
        for (int c = t; c < C4_; c += 256) {
            const float4 a = xr[c];
            float4 hs = {0.f,0.f,0.f,0.f};
            #pragma unroll
            for (int rr = 0; rr < K_; ++rr) {
                const float4 u4 = gb[(size_t)rr * C4_ + c];
                hs.x += u4.x; hs.y += u4.y; hs.z += u4.z; hs.w += u4.w;
            }
            dp += a.x*hs.x + a.y*hs.y + a.z*hs.z + a.w*hs.w;
        }
        dp *= 0.0625f;                          // /K
        dp = wave_reduce_f(dp);
        if (lane == 0) red[t >> 6] = dp;
        __syncthreads();
        if (t == 0) {
            const float ddot = red[0] + red[1] + red[2] + red[3];
            const float d2 = xn[i]*xn[i] + hng2[jj] - 2.0f * ddot;
            const float dist = sqrtf(fmaxf(d2, 1e-12f));
            if (isex) s1x += dist;
            else { const float h = MARGIN_F - dist; if (h > 0.f) l2 += h; }
        }
        __syncthreads();
    }

    if (t == 0) out[0] = (sS1 + s1x) / sC1 + l2 / sNG;
}

// ---------------------------------------------------------------------------
extern "C" void kernel_launch(void* const* d_in, const int* in_sizes, int n_in,
                              void* d_out, int out_size, void* d_ws, size_t ws_size,
                              hipStream_t stream) {
    const float* x    = (const float*)d_in[0];
    const int*   pids = (const int*)d_in[1];

    float* ws = (float*)d_ws;
    float*    dot_part = ws;                                    // 256*16*32 = 131072
    float*    sq_part  = dot_part + P_ * NSL * 32;              // 131072
    float*    hn2_part = sq_part + P_ * NSL * 32;               // 256*16*2 = 8192
    float*    xn       = hn2_part + P_ * NSL * 2;               // 8192
    float*    hng2     = xn + N_;                               // 512
    float*    s1part   = hng2 + TWOP;                           // 32
    unsigned* c1part   = (unsigned*)(s1part + NTAILB);          // 32
    unsigned* negpart  = c1part + NTAILB;                       // 32
    unsigned* counters = negpart + NTAILB;                      // 3: extracnt, flagcnt, ovf
    int*      extralist= (int*)(counters + 3);                  // EXCAP
    int*      flaglist = extralist + EXCAP;                     // FLAGCAP

    hipLaunchKernelGGL(k_fused, dim3(P_ * NSL), dim3(256), 0, stream,
                       x, dot_part, sq_part, hn2_part, counters);
    hipLaunchKernelGGL(k_tail,  dim3(NTAILB),   dim3(256), 0, stream,
                       dot_part, sq_part, hn2_part, pids, xn, hng2,
                       s1part, c1part, negpart, counters, extralist, flaglist);
    hipLaunchKernelGGL(k_final, dim3(1),        dim3(256), 0, stream,
                       x, xn, hng2, s1part, c1part, negpart, counters,
                       extralist, flaglist, (float*)d_out);
}

// Round 4
// 37.588 us; speedup vs baseline: 3.0289x; 1.0623x over previous
//
#include <hip/hip_runtime.h>
#include <math.h>

// Problem constants (fixed by reference setup_inputs)
#define P_    256           // identities
#define K_    16            // instances per group
#define C4_   1024          // float4 per row (C=4096)
#define N_    8192          // 2*P*K rows
#define TWOP  512           // groups
#define NSL   16            // column slices
#define W4    64            // float4 per slice (256 floats)
#define NTAILB 32           // k_tail blocks (32*256 = one thread per row)
#define MARGIN_F 0.6f
#define EXCAP   8192
#define FLAGCAP 16384

__device__ __forceinline__ float wave_reduce_f(float v) {
    #pragma unroll
    for (int o = 32; o > 0; o >>= 1) v += __shfl_xor(v, o, 64);
    return v;
}

// ---------------------------------------------------------------------------
// k_fused: one block per (pair p, slice s). Wave wv holds 8 row-slices in
// registers; centers via LDS partial-sum combine; all 16 per-wave scalars
// (8 dots + 8 sq-norms) reduced with ONE multi-value butterfly (17 shfl).
// x read exactly once. Block 0 zeroes the 4 global counters.
__global__ __launch_bounds__(256) void k_fused(const float* __restrict__ x,
                                               float* __restrict__ dot_part,
                                               float* __restrict__ sq_part,
                                               float* __restrict__ hn2_part,
                                               unsigned* __restrict__ counters) {
    const int blk = blockIdx.x;
    const int p = blk >> 4;          // pair 0..255
    const int s = blk & (NSL - 1);   // slice 0..15
    const int t = threadIdx.x;
    const int lane = t & 63;
    const int wv = t >> 6;           // wave 0..3

    if (blk == 0 && t < 4) counters[t] = 0u;  // extracnt, flagcnt, ovf, done

    __shared__ float4 partA[4][W4];  // 4 KB
    __shared__ float4 partB[4][W4];  // 4 KB
    __shared__ float4 shA[W4];       // 1 KB
    __shared__ float4 shB[W4];       // 1 KB

    const float4* x4 = (const float4*)x;
    const int col = s * W4 + lane;

    // wave wv owns rows r = q*4 + wv: q<4 -> A-rows (grp p), q>=4 -> B-rows
    float4 v[8];
    #pragma unroll
    for (int q = 0; q < 8; ++q) {
        const int r = q * 4 + wv;
        const int grp = (r < 16) ? p : (P_ + p);
        v[q] = x4[((size_t)grp * K_ + (r & 15)) * C4_ + col];
    }
    float4 sA = {0.f,0.f,0.f,0.f}, sB = {0.f,0.f,0.f,0.f};
    #pragma unroll
    for (int q = 0; q < 4; ++q) { sA.x += v[q].x; sA.y += v[q].y; sA.z += v[q].z; sA.w += v[q].w; }
    #pragma unroll
    for (int q = 4; q < 8; ++q) { sB.x += v[q].x; sB.y += v[q].y; sB.z += v[q].z; sB.w += v[q].w; }
    partA[wv][lane] = sA;
    partB[wv][lane] = sB;
    __syncthreads();

    if (wv < 2) {
        const float4* Pp = (wv == 0) ? &partA[0][0] : &partB[0][0];
        const float4 u0 = Pp[0*W4 + lane], u1 = Pp[1*W4 + lane];
        const float4 u2 = Pp[2*W4 + lane], u3 = Pp[3*W4 + lane];
        float4 a;
        a.x = (u0.x+u1.x+u2.x+u3.x) * 0.0625f;
        a.y = (u0.y+u1.y+u2.y+u3.y) * 0.0625f;
        a.z = (u0.z+u1.z+u2.z+u3.z) * 0.0625f;
        a.w = (u0.w+u1.w+u2.w+u3.w) * 0.0625f;
        if (wv == 0) shA[lane] = a; else shB[lane] = a;
        float hn = a.x*a.x + a.y*a.y + a.z*a.z + a.w*a.w;
        hn = wave_reduce_f(hn);
        if (lane == 0) hn2_part[(p * NSL + s) * 2 + wv] = hn;  // 0=A(grp p), 1=B
    }
    __syncthreads();

    const float4 hA = shA[lane];
    const float4 hB = shB[lane];

    // val[0..7] = dot(row q, partner center), val[8..15] = |row q|^2 (per-lane)
    float val[16];
    #pragma unroll
    for (int q = 0; q < 8; ++q) {
        const float4 a = v[q];
        const float4 h = (q < 4) ? hB : hA;   // A-rows pair with B-center etc.
        val[q]     = a.x*h.x + a.y*h.y + a.z*h.z + a.w*h.w;
        val[8 + q] = a.x*a.x + a.y*a.y + a.z*a.z + a.w*a.w;
    }

    // multi-value butterfly: 16 independent 64-lane reductions in 17 shfl.
    #define BFLY_STAGE(MASK, HALF)                                          \
    {                                                                       \
        const bool upper = (lane & MASK) != 0;                              \
        _Pragma("unroll")                                                   \
        for (int i = 0; i < HALF; ++i) {                                    \
            const float send = upper ? val[i] : val[i + HALF];              \
            const float recv = __shfl_xor(send, MASK, 64);                  \
            val[i] = (upper ? val[i + HALF] : val[i]) + recv;               \
        }                                                                   \
    }
    BFLY_STAGE(1, 8)
    BFLY_STAGE(2, 4)
    BFLY_STAGE(4, 2)
    BFLY_STAGE(8, 1)
    #undef BFLY_STAGE
    val[0] += __shfl_xor(val[0], 16, 64);
    val[0] += __shfl_xor(val[0], 32, 64);

    // lane m (m<16) holds the total for value index bitreverse4(m)
    if (lane < 16) {
        const int idx = ((lane & 1) << 3) | ((lane & 2) << 1)
                      | ((lane & 4) >> 1) | ((lane & 8) >> 3);
        const int outbase = (p * NSL + s) * 32;
        if (idx < 8) dot_part[outbase + idx * 4 + wv] = val[0];
        else         sq_part [outbase + (idx - 8) * 4 + wv] = val[0];
    }
}

// ---------------------------------------------------------------------------
// k_tail: one thread per row; slice-combine -> dist; structured fast path or
// exact per-row scan (general pids). Last-arriving block performs the final
// reduction + exact fallback + scalar emit (fence/arrival pattern).
__global__ __launch_bounds__(256) void k_tail(const float* __restrict__ x,
                                              const float* __restrict__ dot_part,
                                              const float* __restrict__ sq_part,
                                              const float* __restrict__ hn2_part,
                                              const int* __restrict__ pids,
                                              float* __restrict__ s1part,
                                              unsigned* __restrict__ c1part,
                                              unsigned* __restrict__ negpart,
                                              unsigned* __restrict__ counters,
                                              int* __restrict__ extralist,
                                              int* __restrict__ flaglist,
                                              float* __restrict__ out) {
    __shared__ int   gp[TWOP];
    __shared__ float shn[TWOP], sh2[TWOP];
    __shared__ int   s_ok, sLast;
    __shared__ float smin[4], smax[4];
    __shared__ float rf[4];
    __shared__ unsigned ru[4], rn[4];
    __shared__ float bc_s1, bc_c1, bc_ng;
    const int t = threadIdx.x;
    const int lane = t & 63, wv = t >> 6;

    if (t == 0) s_ok = 1;
    __syncthreads();

    float lmin = 3.0e38f, lmax = -3.0e38f;
    for (int j = t; j < TWOP; j += 256) {
        const int g = pids[j * K_];
        gp[j] = g;
        if (g != (j & (P_ - 1))) s_ok = 0;   // structured-layout check
        const int side = (j < P_) ? 0 : 1;
        const int pp = j & (P_ - 1);
        float a = 0.f;
        #pragma unroll
        for (int s = 0; s < NSL; ++s) a += hn2_part[(pp * NSL + s) * 2 + side];
        sh2[j] = a;
        const float r = sqrtf(a);
        shn[j] = r;
        lmin = fminf(lmin, r); lmax = fmaxf(lmax, r);
    }
    #pragma unroll
    for (int o = 32; o > 0; o >>= 1) {
        lmin = fminf(lmin, __shfl_xor(lmin, o, 64));
        lmax = fmaxf(lmax, __shfl_xor(lmax, o, 64));
    }
    if (lane == 0) { smin[wv] = lmin; smax[wv] = lmax; }
    __syncthreads();
    const float hmin = fminf(fminf(smin[0], smin[1]), fminf(smin[2], smin[3]));
    const float hmax = fmaxf(fmaxf(smax[0], smax[1]), fmaxf(smax[2], smax[3]));
    const int structured = s_ok;

    const int gr  = blockIdx.x * 256 + t;     // row 0..8191
    const int grp = gr >> 4, kk = gr & 15;
    const int p   = grp & (P_ - 1);
    const int r   = (grp < P_) ? kk : 16 + kk;
    const int pg  = (grp < P_) ? (P_ + p) : p;   // structural partner group

    float dot = 0.f, sq = 0.f;
    #pragma unroll
    for (int s = 0; s < NSL; ++s) {
        dot += dot_part[(p * NSL + s) * 32 + r];
        sq  += sq_part [(p * NSL + s) * 32 + r];
    }
    const float dist = sqrtf(fmaxf(sq + sh2[pg] - 2.0f * dot, 1e-12f));
    const float myxn = sqrtf(sq);
    const int mypid = pids[gr];
    const bool window_clear = (myxn >= hmax + MARGIN_F) || (myxn <= hmin - MARGIN_F);

    unsigned mall, mopp;
    if (structured && mypid == p && window_clear) {
        mall = 2u; mopp = 1u;    // canonical: matches are exactly {p, P_+p}
    } else {
        const int jb = (gr < N_ / 2) ? P_ : 0;
        mall = 0u; mopp = 0u;
        for (int j = 0; j < TWOP; ++j) {
            if (gp[j] == mypid) {
                ++mall;
                if (j >= jb && j < jb + P_) {
                    ++mopp;
                    if (j != pg) {
                        unsigned s0 = atomicAdd(&counters[0], 1u);
                        if (s0 < EXCAP) extralist[s0] = gr * TWOP + j;
                        else atomicExch(&counters[2], 1u);
                    }
                }
            } else if (fabsf(myxn - shn[j]) < MARGIN_F) {
                unsigned s0 = atomicAdd(&counters[1], 1u);
                if (s0 < FLAGCAP) flaglist[s0] = gr * TWOP + j;
                else atomicExch(&counters[2], 1u);
            }
        }
    }

    float s1 = (gp[pg] == mypid) ? dist : 0.f;
    unsigned neg = (unsigned)TWOP - mall;
    unsigned mo = mopp;
    #pragma unroll
    for (int o = 32; o > 0; o >>= 1) {
        s1  += __shfl_xor(s1, o, 64);
        mo  += __shfl_xor(mo, o, 64);
        neg += __shfl_xor(neg, o, 64);
    }
    if (lane == 0) { rf[wv] = s1; ru[wv] = mo; rn[wv] = neg; }
    __syncthreads();
    if (t == 0) {
        atomicExch(&s1part[blockIdx.x],  rf[0] + rf[1] + rf[2] + rf[3]);
        atomicExch(&c1part[blockIdx.x],  ru[0] + ru[1] + ru[2] + ru[3]);
        atomicExch(&negpart[blockIdx.x], rn[0] + rn[1] + rn[2] + rn[3]);
    }

    // ---- arrival: last block performs final phase
    __threadfence();
    if (t == 0) {
        const unsigned n = atomicAdd(&counters[3], 1u);
        sLast = (n == NTAILB - 1) ? 1 : 0;
    }
    __syncthreads();
    if (!sLast) return;
    __threadfence();   // acquire: see all blocks' partials/lists

    // reduce the 32 block partials (fixed order -> deterministic)
    {
        float s1v = 0.f; unsigned c1v = 0u, ngv = 0u;
        if (t < NTAILB) { s1v = s1part[t]; c1v = c1part[t]; ngv = negpart[t]; }
        if (t < 64) {
            #pragma unroll
            for (int o = 32; o > 0; o >>= 1) {
                s1v += __shfl_xor(s1v, o, 64);
                c1v += __shfl_xor(c1v, o, 64);
                ngv += __shfl_xor(ngv, o, 64);
            }
            if (t == 0) { bc_s1 = s1v; bc_c1 = (float)c1v; bc_ng = (float)ngv; }
        }
    }
    __syncthreads();

    // exact fallback for extras (loss1) and flagged pairs (hinge); expected 0
    unsigned ne = counters[0]; if (ne > EXCAP)   ne = EXCAP;
    unsigned nf = counters[1]; if (nf > FLAGCAP) nf = FLAGCAP;
    float s1x = 0.f, l2 = 0.f;
    const float4* x4 = (const float4*)x;
    for (unsigned u = 0; u < ne + nf; ++u) {
        const bool isex = (u < ne);
        const int code = isex ? extralist[u] : flaglist[u - ne];
        const int i = code >> 9, jj = code & (TWOP - 1);
        const float4* xr = x4 + (size_t)i * C4_;
        const float4* gb = x4 + (size_t)jj * K_ * C4_;
        float dp = 0.f, sqi = 0.f;
        for (int c = t; c < C4_; c += 256) {
            const float4 a = xr[c];
            float hx = 0.f, hy = 0.f, hz = 0.f, hw = 0.f;
            #pragma unroll
            for (int rr = 0; rr < K_; ++rr) {
                const float4 u4 = gb[(size_t)rr * C4_ + c];
                hx += u4.x; hy += u4.y; hz += u4.z; hw += u4.w;
            }
            dp  += (a.x*hx + a.y*hy + a.z*hz + a.w*hw) * 0.0625f;
            sqi += a.x*a.x + a.y*a.y + a.z*a.z + a.w*a.w;
        }
        #pragma unroll
        for (int o = 32; o > 0; o >>= 1) {
            dp  += __shfl_xor(dp, o, 64);
            sqi += __shfl_xor(sqi, o, 64);
        }
        if (lane == 0) { rf[wv] = dp; smin[wv] = sqi; }
        __syncthreads();
        if (t == 0) {
            const float ddot = rf[0] + rf[1] + rf[2] + rf[3];
            const float sqv  = smin[0] + smin[1] + smin[2] + smin[3];
            const float d2 = sqv + sh2[jj] - 2.0f * ddot;
            const float dist2 = sqrtf(fmaxf(d2, 1e-12f));
            if (isex) s1x += dist2;
            else { const float h = MARGIN_F - dist2; if (h > 0.f) l2 += h; }
        }
        __syncthreads();
    }

    if (t == 0) out[0] = (bc_s1 + s1x) / bc_c1 + l2 / bc_ng;
}

// ---------------------------------------------------------------------------
extern "C" void kernel_launch(void* const* d_in, const int* in_sizes, int n_in,
                              void* d_out, int out_size, void* d_ws, size_t ws_size,
                              hipStream_t stream) {
    const float* x    = (const float*)d_in[0];
    const int*   pids = (const int*)d_in[1];

    float* ws = (float*)d_ws;
    float*    dot_part = ws;                                    // 131072
    float*    sq_part  = dot_part + P_ * NSL * 32;              // 131072
    float*    hn2_part = sq_part + P_ * NSL * 32;               // 8192
    float*    s1part   = hn2_part + P_ * NSL * 2;               // 32
    unsigned* c1part   = (unsigned*)(s1part + NTAILB);          // 32
    unsigned* negpart  = c1part + NTAILB;                       // 32
    unsigned* counters = negpart + NTAILB;                      // 4
    int*      extralist= (int*)(counters + 4);                  // EXCAP
    int*      flaglist = extralist + EXCAP;                     // FLAGCAP

    hipLaunchKernelGGL(k_fused, dim3(P_ * NSL), dim3(256), 0, stream,
                       x, dot_part, sq_part, hn2_part, counters);
    hipLaunchKernelGGL(k_tail,  dim3(NTAILB),   dim3(256), 0, stream,
                       x, dot_part, sq_part, hn2_part, pids,
                       s1part, c1part, negpart, counters,
                       extralist, flaglist, (float*)d_out);
}

// Round 5
// 35.133 us; speedup vs baseline: 3.2406x; 1.0699x over previous
//
#include <hip/hip_runtime.h>
#include <math.h>

// Problem constants (fixed by reference setup_inputs)
#define P_    256           // identities
#define K_    16            // instances per group
#define C4_   1024          // float4 per row (C=4096)
#define N_    8192          // 2*P*K rows
#define TWOP  512           // groups
#define NSL   8             // column slices (each 128 float4 = 512 floats)
#define NTAILB 32           // k_tail blocks (32*256 = one thread per row)
#define MARGIN_F 0.6f
#define EXCAP   8192
#define FLAGCAP 16384

__device__ __forceinline__ float wave_reduce_f(float v) {
    #pragma unroll
    for (int o = 32; o > 0; o >>= 1) v += __shfl_xor(v, o, 64);
    return v;
}

// ---------------------------------------------------------------------------
// k_fused: one block per (pair p, slice s); slice = 128 float4 (two 64-lane
// chunks). Wave wv holds 8 row-slices (4 A-rows + 4 B-rows) x 2 chunks in
// registers (16 float4). Centers via LDS partial combine (all 4 waves busy:
// A0/A1/B0/B1). 16 per-wave scalars reduced with one multi-value butterfly.
// x read exactly once. Block 0 zeroes the 4 global counters.
__global__ __launch_bounds__(256) void k_fused(const float* __restrict__ x,
                                               float* __restrict__ dot_part,
                                               float* __restrict__ sq_part,
                                               float* __restrict__ hn2_part,
                                               unsigned* __restrict__ counters) {
    const int blk = blockIdx.x;
    const int p = blk >> 3;          // pair 0..255
    const int s = blk & (NSL - 1);   // slice 0..7
    const int t = threadIdx.x;
    const int lane = t & 63;
    const int wv = t >> 6;           // wave 0..3

    if (blk == 0 && t < 4) counters[t] = 0u;  // extracnt, flagcnt, ovf, done

    __shared__ float4 part[4][4][64];  // [wave][task A0,A1,B0,B1][lane] 16 KB
    __shared__ float4 sh[4][64];       // [task][lane] center chunks    4 KB

    const float4* x4 = (const float4*)x;
    const int col0 = s * 128 + lane;

    // wave wv owns rows r = q*4 + wv: q<4 -> A-rows (grp p), q>=4 -> B-rows
    float4 v0[8], v1[8];
    #pragma unroll
    for (int q = 0; q < 8; ++q) {
        const int r = q * 4 + wv;
        const int grp = (r < 16) ? p : (P_ + p);
        const size_t base = ((size_t)grp * K_ + (r & 15)) * C4_ + col0;
        v0[q] = x4[base];
        v1[q] = x4[base + 64];
    }
    float4 sA0 = {0,0,0,0}, sA1 = sA0, sB0 = sA0, sB1 = sA0;
    #pragma unroll
    for (int q = 0; q < 4; ++q) {
        sA0.x += v0[q].x; sA0.y += v0[q].y; sA0.z += v0[q].z; sA0.w += v0[q].w;
        sA1.x += v1[q].x; sA1.y += v1[q].y; sA1.z += v1[q].z; sA1.w += v1[q].w;
    }
    #pragma unroll
    for (int q = 4; q < 8; ++q) {
        sB0.x += v0[q].x; sB0.y += v0[q].y; sB0.z += v0[q].z; sB0.w += v0[q].w;
        sB1.x += v1[q].x; sB1.y += v1[q].y; sB1.z += v1[q].z; sB1.w += v1[q].w;
    }
    part[wv][0][lane] = sA0;
    part[wv][1][lane] = sA1;
    part[wv][2][lane] = sB0;
    part[wv][3][lane] = sB1;
    __syncthreads();

    // combine: wave wv handles task wv (A-chunk0, A-chunk1, B-chunk0, B-chunk1)
    {
        const float4 u0 = part[0][wv][lane], u1 = part[1][wv][lane];
        const float4 u2 = part[2][wv][lane], u3 = part[3][wv][lane];
        float4 a;
        a.x = (u0.x+u1.x+u2.x+u3.x) * 0.0625f;
        a.y = (u0.y+u1.y+u2.y+u3.y) * 0.0625f;
        a.z = (u0.z+u1.z+u2.z+u3.z) * 0.0625f;
        a.w = (u0.w+u1.w+u2.w+u3.w) * 0.0625f;
        sh[wv][lane] = a;
        float hn = a.x*a.x + a.y*a.y + a.z*a.z + a.w*a.w;
        hn = wave_reduce_f(hn);
        // task wv: 0=A.c0, 1=A.c1, 2=B.c0, 3=B.c1 (side = wv>>1)
        if (lane == 0) hn2_part[(p * NSL + s) * 4 + wv] = hn;
    }
    __syncthreads();

    const float4 hA0 = sh[0][lane], hA1 = sh[1][lane];
    const float4 hB0 = sh[2][lane], hB1 = sh[3][lane];

    // val[0..7] = dot(row q, partner center), val[8..15] = |row q|^2 (per-lane)
    float val[16];
    #pragma unroll
    for (int q = 0; q < 8; ++q) {
        const float4 a0 = v0[q], a1 = v1[q];
        const float4 h0 = (q < 4) ? hB0 : hA0;
        const float4 h1 = (q < 4) ? hB1 : hA1;
        val[q]     = a0.x*h0.x + a0.y*h0.y + a0.z*h0.z + a0.w*h0.w
                   + a1.x*h1.x + a1.y*h1.y + a1.z*h1.z + a1.w*h1.w;
        val[8 + q] = a0.x*a0.x + a0.y*a0.y + a0.z*a0.z + a0.w*a0.w
                   + a1.x*a1.x + a1.y*a1.y + a1.z*a1.z + a1.w*a1.w;
    }

    // multi-value butterfly: 16 independent 64-lane reductions in 17 shfl.
    #define BFLY_STAGE(MASK, HALF)                                          \
    {                                                                       \
        const bool upper = (lane & MASK) != 0;                              \
        _Pragma("unroll")                                                   \
        for (int i = 0; i < HALF; ++i) {                                    \
            const float send = upper ? val[i] : val[i + HALF];              \
            const float recv = __shfl_xor(send, MASK, 64);                  \
            val[i] = (upper ? val[i + HALF] : val[i]) + recv;               \
        }                                                                   \
    }
    BFLY_STAGE(1, 8)
    BFLY_STAGE(2, 4)
    BFLY_STAGE(4, 2)
    BFLY_STAGE(8, 1)
    #undef BFLY_STAGE
    val[0] += __shfl_xor(val[0], 16, 64);
    val[0] += __shfl_xor(val[0], 32, 64);

    // lane m (m<16) holds the total for value index bitreverse4(m)
    if (lane < 16) {
        const int idx = ((lane & 1) << 3) | ((lane & 2) << 1)
                      | ((lane & 4) >> 1) | ((lane & 8) >> 3);
        const int outbase = (p * NSL + s) * 32;
        if (idx < 8) dot_part[outbase + idx * 4 + wv] = val[0];
        else         sq_part [outbase + (idx - 8) * 4 + wv] = val[0];
    }
}

// ---------------------------------------------------------------------------
// k_tail: one thread per row; slice-combine -> dist; structured fast path or
// exact per-row scan (general pids). Last-arriving block performs the final
// reduction + exact fallback + scalar emit (fence/arrival pattern).
__global__ __launch_bounds__(256) void k_tail(const float* __restrict__ x,
                                              const float* __restrict__ dot_part,
                                              const float* __restrict__ sq_part,
                                              const float* __restrict__ hn2_part,
                                              const int* __restrict__ pids,
                                              float* __restrict__ s1part,
                                              unsigned* __restrict__ c1part,
                                              unsigned* __restrict__ negpart,
                                              unsigned* __restrict__ counters,
                                              int* __restrict__ extralist,
                                              int* __restrict__ flaglist,
                                              float* __restrict__ out) {
    __shared__ int   gp[TWOP];
    __shared__ float shn[TWOP], sh2[TWOP];
    __shared__ int   s_ok, sLast;
    __shared__ float smin[4], smax[4];
    __shared__ float rf[4];
    __shared__ unsigned ru[4], rn[4];
    __shared__ float bc_s1, bc_c1, bc_ng;
    const int t = threadIdx.x;
    const int lane = t & 63, wv = t >> 6;

    if (t == 0) s_ok = 1;
    __syncthreads();

    float lmin = 3.0e38f, lmax = -3.0e38f;
    for (int j = t; j < TWOP; j += 256) {
        const int g = pids[j * K_];
        gp[j] = g;
        if (g != (j & (P_ - 1))) s_ok = 0;   // structured-layout check
        const int side = (j < P_) ? 0 : 1;
        const int pp = j & (P_ - 1);
        float a = 0.f;
        #pragma unroll
        for (int s = 0; s < NSL; ++s) {
            a += hn2_part[(pp * NSL + s) * 4 + side * 2];
            a += hn2_part[(pp * NSL + s) * 4 + side * 2 + 1];
        }
        sh2[j] = a;
        const float r = sqrtf(a);
        shn[j] = r;
        lmin = fminf(lmin, r); lmax = fmaxf(lmax, r);
    }
    #pragma unroll
    for (int o = 32; o > 0; o >>= 1) {
        lmin = fminf(lmin, __shfl_xor(lmin, o, 64));
        lmax = fmaxf(lmax, __shfl_xor(lmax, o, 64));
    }
    if (lane == 0) { smin[wv] = lmin; smax[wv] = lmax; }
    __syncthreads();
    const float hmin = fminf(fminf(smin[0], smin[1]), fminf(smin[2], smin[3]));
    const float hmax = fmaxf(fmaxf(smax[0], smax[1]), fmaxf(smax[2], smax[3]));
    const int structured = s_ok;

    const int gr  = blockIdx.x * 256 + t;     // row 0..8191
    const int grp = gr >> 4, kk = gr & 15;
    const int p   = grp & (P_ - 1);
    const int r   = (grp < P_) ? kk : 16 + kk;
    const int pg  = (grp < P_) ? (P_ + p) : p;   // structural partner group

    float dot = 0.f, sq = 0.f;
    #pragma unroll
    for (int s = 0; s < NSL; ++s) {
        dot += dot_part[(p * NSL + s) * 32 + r];
        sq  += sq_part [(p * NSL + s) * 32 + r];
    }
    const float dist = sqrtf(fmaxf(sq + sh2[pg] - 2.0f * dot, 1e-12f));
    const float myxn = sqrtf(sq);
    const int mypid = pids[gr];
    const bool window_clear = (myxn >= hmax + MARGIN_F) || (myxn <= hmin - MARGIN_F);

    unsigned mall, mopp;
    if (structured && mypid == p && window_clear) {
        mall = 2u; mopp = 1u;    // canonical: matches are exactly {p, P_+p}
    } else {
        const int jb = (gr < N_ / 2) ? P_ : 0;
        mall = 0u; mopp = 0u;
        for (int j = 0; j < TWOP; ++j) {
            if (gp[j] == mypid) {
                ++mall;
                if (j >= jb && j < jb + P_) {
                    ++mopp;
                    if (j != pg) {
                        unsigned s0 = atomicAdd(&counters[0], 1u);
                        if (s0 < EXCAP) extralist[s0] = gr * TWOP + j;
                        else atomicExch(&counters[2], 1u);
                    }
                }
            } else if (fabsf(myxn - shn[j]) < MARGIN_F) {
                unsigned s0 = atomicAdd(&counters[1], 1u);
                if (s0 < FLAGCAP) flaglist[s0] = gr * TWOP + j;
                else atomicExch(&counters[2], 1u);
            }
        }
    }

    float s1 = (gp[pg] == mypid) ? dist : 0.f;
    unsigned neg = (unsigned)TWOP - mall;
    unsigned mo = mopp;
    #pragma unroll
    for (int o = 32; o > 0; o >>= 1) {
        s1  += __shfl_xor(s1, o, 64);
        mo  += __shfl_xor(mo, o, 64);
        neg += __shfl_xor(neg, o, 64);
    }
    if (lane == 0) { rf[wv] = s1; ru[wv] = mo; rn[wv] = neg; }
    __syncthreads();
    if (t == 0) {
        atomicExch(&s1part[blockIdx.x],  rf[0] + rf[1] + rf[2] + rf[3]);
        atomicExch(&c1part[blockIdx.x],  ru[0] + ru[1] + ru[2] + ru[3]);
        atomicExch(&negpart[blockIdx.x], rn[0] + rn[1] + rn[2] + rn[3]);
    }

    // ---- arrival: last block performs final phase
    __threadfence();
    if (t == 0) {
        const unsigned n = atomicAdd(&counters[3], 1u);
        sLast = (n == NTAILB - 1) ? 1 : 0;
    }
    __syncthreads();
    if (!sLast) return;
    __threadfence();   // acquire: see all blocks' partials/lists

    // reduce the 32 block partials (fixed order -> deterministic)
    {
        float s1v = 0.f; unsigned c1v = 0u, ngv = 0u;
        if (t < NTAILB) { s1v = s1part[t]; c1v = c1part[t]; ngv = negpart[t]; }
        if (t < 64) {
            #pragma unroll
            for (int o = 32; o > 0; o >>= 1) {
                s1v += __shfl_xor(s1v, o, 64);
                c1v += __shfl_xor(c1v, o, 64);
                ngv += __shfl_xor(ngv, o, 64);
            }
            if (t == 0) { bc_s1 = s1v; bc_c1 = (float)c1v; bc_ng = (float)ngv; }
        }
    }
    __syncthreads();

    // exact fallback for extras (loss1) and flagged pairs (hinge); expected 0
    unsigned ne = counters[0]; if (ne > EXCAP)   ne = EXCAP;
    unsigned nf = counters[1]; if (nf > FLAGCAP) nf = FLAGCAP;
    float s1x = 0.f, l2 = 0.f;
    const float4* x4 = (const float4*)x;
    for (unsigned u = 0; u < ne + nf; ++u) {
        const bool isex = (u < ne);
        const int code = isex ? extralist[u] : flaglist[u - ne];
        const int i = code >> 9, jj = code & (TWOP - 1);
        const float4* xr = x4 + (size_t)i * C4_;
        const float4* gb = x4 + (size_t)jj * K_ * C4_;
        float dp = 0.f, sqi = 0.f;
        for (int c = t; c < C4_; c += 256) {
            const float4 a = xr[c];
            float hx = 0.f, hy = 0.f, hz = 0.f, hw = 0.f;
            #pragma unroll
            for (int rr = 0; rr < K_; ++rr) {
                const float4 u4 = gb[(size_t)rr * C4_ + c];
                hx += u4.x; hy += u4.y; hz += u4.z; hw += u4.w;
            }
            dp  += (a.x*hx + a.y*hy + a.z*hz + a.w*hw) * 0.0625f;
            sqi += a.x*a.x + a.y*a.y + a.z*a.z + a.w*a.w;
        }
        #pragma unroll
        for (int o = 32; o > 0; o >>= 1) {
            dp  += __shfl_xor(dp, o, 64);
            sqi += __shfl_xor(sqi, o, 64);
        }
        if (lane == 0) { rf[wv] = dp; smin[wv] = sqi; }
        __syncthreads();
        if (t == 0) {
            const float ddot = rf[0] + rf[1] + rf[2] + rf[3];
            const float sqv  = smin[0] + smin[1] + smin[2] + smin[3];
            const float d2 = sqv + sh2[jj] - 2.0f * ddot;
            const float dist2 = sqrtf(fmaxf(d2, 1e-12f));
            if (isex) s1x += dist2;
            else { const float h = MARGIN_F - dist2; if (h > 0.f) l2 += h; }
        }
        __syncthreads();
    }

    if (t == 0) out[0] = (bc_s1 + s1x) / bc_c1 + l2 / bc_ng;
}

// ---------------------------------------------------------------------------
extern "C" void kernel_launch(void* const* d_in, const int* in_sizes, int n_in,
                              void* d_out, int out_size, void* d_ws, size_t ws_size,
                              hipStream_t stream) {
    const float* x    = (const float*)d_in[0];
    const int*   pids = (const int*)d_in[1];

    float* ws = (float*)d_ws;
    float*    dot_part = ws;                                    // 256*8*32 = 65536
    float*    sq_part  = dot_part + P_ * NSL * 32;              // 65536
    float*    hn2_part = sq_part + P_ * NSL * 32;               // 256*8*4 = 8192
    float*    s1part   = hn2_part + P_ * NSL * 4;               // 32
    unsigned* c1part   = (unsigned*)(s1part + NTAILB);          // 32
    unsigned* negpart  = c1part + NTAILB;                       // 32
    unsigned* counters = negpart + NTAILB;                      // 4
    int*      extralist= (int*)(counters + 4);                  // EXCAP
    int*      flaglist = extralist + EXCAP;                     // FLAGCAP

    hipLaunchKernelGGL(k_fused, dim3(P_ * NSL), dim3(256), 0, stream,
                       x, dot_part, sq_part, hn2_part, counters);
    hipLaunchKernelGGL(k_tail,  dim3(NTAILB),   dim3(256), 0, stream,
                       x, dot_part, sq_part, hn2_part, pids,
                       s1part, c1part, negpart, counters,
                       extralist, flaglist, (float*)d_out);
}